// Round 19
// baseline (249.133 us; speedup 1.0000x reference)
//
#include <hip/hip_runtime.h>
#include <hip/hip_bf16.h>

typedef __attribute__((ext_vector_type(8))) short short8;
typedef __attribute__((ext_vector_type(4))) short short4v;
typedef __attribute__((ext_vector_type(4))) float float4v;

#define DEVI static __device__ __forceinline__

#if __has_builtin(__builtin_amdgcn_exp2f)
#define EXP2(x) __builtin_amdgcn_exp2f(x)
#else
#define EXP2(x) exp2f(x)
#endif

DEVI unsigned short f2bf(float f) {
  unsigned int u = __builtin_bit_cast(unsigned int, f);
  u += 0x7fffu + ((u >> 16) & 1u);
  return (unsigned short)(u >> 16);
}

DEVI float bf2f(unsigned short s) {
  return __builtin_bit_cast(float, ((unsigned)s) << 16);
}

// vendor-emitted packed f32->bf16 (v_cvt_pk_bf16_f32); NEVER hand-rolled asm (r5/r6 NaN)
DEVI short8 pack8(float4v a, float4v b) {  // elems 0..3 <- a, 4..7 <- b
  struct P4 { __hip_bfloat162 x, y, z, w; } t;
  t.x = __float22bfloat162_rn(make_float2(a[0], a[1]));
  t.y = __float22bfloat162_rn(make_float2(a[2], a[3]));
  t.z = __float22bfloat162_rn(make_float2(b[0], b[1]));
  t.w = __float22bfloat162_rn(make_float2(b[2], b[3]));
  short8 r;
  __builtin_memcpy(&r, &t, 16);
  return r;
}

DEVI short4v pack4(float a, float b, float c, float d) {
  struct P2 { __hip_bfloat162 x, y; } t;
  t.x = __float22bfloat162_rn(make_float2(a, b));
  t.y = __float22bfloat162_rn(make_float2(c, d));
  short4v r;
  __builtin_memcpy(&r, &t, 8);
  return r;
}

DEVI void gload16(const void* src, void* lds_dst) {
  __builtin_amdgcn_global_load_lds(
      (const __attribute__((address_space(1))) void*)src,
      (__attribute__((address_space(3))) void*)lds_dst, 16, 0, 0);
}

// f32 -> bf16 elementwise (for Wq, Wo): 8 elems/thread
__global__ __launch_bounds__(256)
void cvt_bf16(const float* __restrict__ in, unsigned short* __restrict__ out, int n8)
{
  int i = blockIdx.x * 256 + threadIdx.x;
  if (i < n8) {
    float4v a = *(const float4v*)(in + (size_t)i * 8);
    float4v b = *(const float4v*)(in + (size_t)i * 8 + 4);
    *(short8*)(out + (size_t)i * 8) = pack8(a, b);
  }
}

// C = A[M x K] * B[Nc x K]^T.  B is bf16 (pre-converted), staged via gload16
// into linear [128 row][64B] LDS (m97 layout).  [r18-proven, unchanged]
// AF32: 1 = A f32, reg-staged+converted; 0 = A bf16 via gload16.
// CMODE: 0 = bf16 row-major C (scaled); 1 = f32 row-major;
//        2 = bf16 TRANSPOSED CT[Nc][M], m permuted in 32-blocks
//            (32q+16h'+4c'+i -> 32q+8c'+4h'+i) for the attn PV b128 read.
template<int AF32, int CMODE>
__global__ __launch_bounds__(256, 2)
void gemm_bt128(const void* __restrict__ Ap, const unsigned short* __restrict__ Bp,
                void* __restrict__ Cp, int M, int Nc, int Kd, float oscale)
{
  constexpr int AS = AF32 ? 40 : 32;            // A row stride in shorts
  __shared__ alignas(16) short As[2][128 * AS];
  __shared__ alignas(16) short Bs[2][128 * 32];

  const int tid = threadIdx.x;
  const int lane = tid & 63;
  const int wid = tid >> 6;
  const int rl = lane & 15;
  const int g = lane >> 4;
  const int bm = blockIdx.x * 128;
  const int bn = blockIdx.y * 128;
  const int wm = (wid >> 1) * 64;
  const int wn = (wid & 1) * 64;
  const int srow = tid >> 1;          // 0..127 (AF32 A-staging)
  const int k0 = (tid & 1) * 16;      // 0 or 16

  float4v acc[4][4];
#pragma unroll
  for (int i = 0; i < 4; ++i)
#pragma unroll
    for (int j = 0; j < 4; ++j) acc[i][j] = (float4v)(0.0f);

  const float* Af = (const float*)Ap;
  const unsigned short* Ab = (const unsigned short*)Ap;

  float4v afr[4];
  short8 ah[2];

  const int NK = Kd >> 5;

  const int grow = tid >> 2;
  const int gchk = tid & 3;

  auto stageB = [&](int ks, int b) {
#pragma unroll
    for (int j = 0; j < 2; ++j) {
      const unsigned short* src = Bp + (size_t)(bn + grow + j * 64) * Kd + ks * 32 + gchk * 8;
      gload16(src, (char*)Bs[b] + j * 4096 + wid * 1024);
    }
  };
  auto stageA16 = [&](int ks, int b) {
#pragma unroll
    for (int j = 0; j < 2; ++j) {
      const unsigned short* src = Ab + (size_t)(bm + grow + j * 64) * Kd + ks * 32 + gchk * 8;
      gload16(src, (char*)As[b] + j * 4096 + wid * 1024);
    }
  };
  auto loadA = [&](int ks) {
    size_t base = (size_t)(bm + srow) * Kd + ks * 32 + k0;
    afr[0] = *(const float4v*)(Af + base);
    afr[1] = *(const float4v*)(Af + base + 4);
    afr[2] = *(const float4v*)(Af + base + 8);
    afr[3] = *(const float4v*)(Af + base + 12);
  };
  auto packWriteA = [&](int b) {
    ah[0] = pack8(afr[0], afr[1]);
    ah[1] = pack8(afr[2], afr[3]);
    *(short8*)(As[b] + srow * 40 + k0)     = ah[0];
    *(short8*)(As[b] + srow * 40 + k0 + 8) = ah[1];
  };

  stageB(0, 0);
  if constexpr (AF32 != 0) {
    loadA(0);
    packWriteA(0);
  } else {
    stageA16(0, 0);
  }
  __syncthreads();

  for (int ks = 0; ks < NK; ++ks) {
    const int b = ks & 1;
    if (ks + 1 < NK) {
      stageB(ks + 1, b ^ 1);
      if constexpr (AF32 != 0) loadA(ks + 1);
      else stageA16(ks + 1, b ^ 1);
    }

    short8 a8[4], b8[4];
#pragma unroll
    for (int mt = 0; mt < 4; ++mt)
      a8[mt] = *(const short8*)(As[b] + (wm + mt * 16 + rl) * AS + 8 * g);
#pragma unroll
    for (int nt = 0; nt < 4; ++nt)
      b8[nt] = *(const short8*)(Bs[b] + (wn + nt * 16 + rl) * 32 + 8 * g);
#pragma unroll
    for (int mt = 0; mt < 4; ++mt)
#pragma unroll
      for (int nt = 0; nt < 4; ++nt)
        acc[mt][nt] = __builtin_amdgcn_mfma_f32_16x16x32_bf16(a8[mt], b8[nt], acc[mt][nt], 0, 0, 0);

    if constexpr (AF32 != 0)
      if (ks + 1 < NK) packWriteA(b ^ 1);
    __syncthreads();
  }

#pragma unroll
  for (int mt = 0; mt < 4; ++mt)
#pragma unroll
    for (int nt = 0; nt < 4; ++nt) {
      const int col = bn + wn + nt * 16 + rl;
      const int row0 = bm + wm + mt * 16 + 4 * g;
      if constexpr (CMODE == 1) {
        float* C = (float*)Cp;
#pragma unroll
        for (int r = 0; r < 4; ++r)
          C[(size_t)(row0 + r) * Nc + col] = acc[mt][nt][r];
      } else if constexpr (CMODE == 0) {
        unsigned short* C = (unsigned short*)Cp;
#pragma unroll
        for (int r = 0; r < 4; ++r)
          C[(size_t)(row0 + r) * Nc + col] = f2bf(acc[mt][nt][r] * oscale);
      } else {  // CMODE==2: transposed + 32-block permutation
        unsigned short* C = (unsigned short*)Cp;
        short4v w = pack4(acc[mt][nt][0], acc[mt][nt][1], acc[mt][nt][2], acc[mt][nt][3]);
        const int u = row0 & 31;
        const int pm = (row0 & ~31) | (((u >> 2) & 3) << 3) | (((u >> 4) & 1) << 2);
        *(short4v*)(C + (size_t)col * M + pm) = w;
      }
    }
}

// Fused attention, softmax over batch axis n (size 4) — L-WIDE waves.
// Grid (16,16), 512 threads = 8 waves. Wave (lg = wid&3, nh = wid>>2) owns
// 32 l-rows (l0 = bx*128 + lg*32, two 16-row subtiles) and 2 n (n0 = 2nh).
// K/V fragments are REUSED across the two l-subtiles -> per-wave LDS reads
// halve vs r18 (16KB vs 32KB per tile) while MFMA count/wave is unchanged.
// Softmax over n crosses the wave pair (nh, nh^1): per-lane bf16-packed
// partial sums (32B) exchanged via LDS + one extra (non-draining) s_barrier.
// All fragment layouts = r17/r18-verified 16x16 machinery.
// LDS: 4 x 32KB K/V buffers (counted-vmcnt, 3 stages in flight) + 16KB exchange.
//   K: 4n x [32 s][128B], 16B chunk c holds global chunk c^(s&7).
//   V^T: 4n x [64 dk][64B]; data chunk c at phys chunk c^((dk>>1)&3) (s-permuted
//        globally by the V-GEMM so PV's K=32 A-frag is one b128).
__global__ __launch_bounds__(512, 2)
void attn_bn(const unsigned short* __restrict__ qb,
             const unsigned short* __restrict__ kb,
             const unsigned short* __restrict__ vtb,
             unsigned short* __restrict__ hb)
{
  __shared__ alignas(128) char smem[147456];  // 4*32KB + 16KB exchange

  const int tid = threadIdx.x;
  const int lane = tid & 63;
  const int wid = tid >> 6;          // 0..7
  const int rl = lane & 15;
  const int g = lane >> 4;
  const int h = blockIdx.y;
  const int lg = wid & 3;
  const int nh = wid >> 2;           // n-half: n0 = 2*nh
  const int n0 = nh * 2;
  const int l0 = blockIdx.x * 128 + lg * 32;

  // q B-fragments: qf[j][lt][dh], lane holds q[l0+lt*16+rl][h*64 + dh*32 + 8g + i]
  short8 qf[2][2][2];
#pragma unroll
  for (int j = 0; j < 2; ++j)
#pragma unroll
    for (int lt = 0; lt < 2; ++lt)
#pragma unroll
      for (int dh = 0; dh < 2; ++dh)
        qf[j][lt][dh] = *(const short8*)(qb
            + (size_t)((n0 + j) * 2048 + l0 + lt * 16 + rl) * 1024 + h * 64 + dh * 32 + 8 * g);

  float4v ha[2][2][4];  // [j][lt][t4]: heads^T acc, dk rows 16t4.., cols l-subtile lt
#pragma unroll
  for (int j = 0; j < 2; ++j)
#pragma unroll
    for (int lt = 0; lt < 2; ++lt)
#pragma unroll
      for (int t = 0; t < 4; ++t) ha[j][lt][t] = (float4v)(0.0f);

  // staging (roles by wid, independent of compute roles): waves 0-3 K (n=wid),
  // waves 4-7 V^T (n=wid-4). 4 gload16 each.  [r18-identical]
  const size_t koff0 = ((size_t)(wid * 2048) + (size_t)(lane >> 3)) * 1024
                     + (size_t)(h * 64) + (size_t)(((lane & 7) ^ (lane >> 3)) * 8);
  const size_t voff0 = ((size_t)(h * 64) + (size_t)(lane >> 2)) * 8192
                     + (size_t)((wid - 4) * 2048)
                     + (size_t)((((lane & 3) ^ ((lane >> 3) & 3)) * 8));

  auto stage = [&](int step, int b) {
    if (wid < 4) {
      char* kdst = smem + b * 32768 + wid * 4096;
      const unsigned short* ksrc = kb + koff0 + (size_t)step * 32 * 1024;
#pragma unroll
      for (int ii = 0; ii < 4; ++ii)
        gload16(ksrc + ii * 8192, kdst + ii * 1024);
    } else {
      char* vdst = smem + b * 32768 + 16384 + (wid - 4) * 4096;
      const unsigned short* vsrc = vtb + voff0 + (size_t)step * 32;
#pragma unroll
      for (int ii = 0; ii < 4; ++ii)
        gload16(vsrc + (size_t)ii * 16 * 8192, vdst + ii * 1024);
    }
  };

  stage(0, 0);
  stage(1, 1);
  stage(2, 2);
  asm volatile("s_waitcnt vmcnt(8)" ::: "memory");
  __builtin_amdgcn_s_barrier();

  const unsigned voffr = ((unsigned)(g ^ ((rl >> 1) & 3))) << 4;
  // exchange slots: 32B per lane per wave; partner = wid^4 (same lg, other nh)
  char* exW = smem + 131072 + wid * 2048 + lane * 32;
  char* exR = smem + 131072 + (wid ^ 4) * 2048 + lane * 32;

  for (int to = 0; to < 16; ++to) {
#pragma unroll
    for (int ti = 0; ti < 4; ++ti) {
      const int t = to * 4 + ti;
      char* kbase = smem + ti * 32768;   // compile-time buffer base
      char* vbase = kbase + 16384;

      // QK for own 2 n, both l-subtiles (K-frags reused across lt).
      // scores^T C[s][l]: lane s = ss*16 + 4g + r, l = l0 + lt*16 + rl.
      float4v sc[2][2][2];  // [j][lt][ss]
#pragma unroll
      for (int j = 0; j < 2; ++j) {
        char* kn = kbase + (n0 + j) * 4096;
#pragma unroll
        for (int ss = 0; ss < 2; ++ss) {
          const int srw = ss * 16 + rl;
          const unsigned sw = ((unsigned)(srw & 7)) << 4;
          short8 kf0 = *(const short8*)(kn + srw * 128 + ((16u * (unsigned)g) ^ sw));
          short8 kf1 = *(const short8*)(kn + srw * 128 + ((64u + 16u * (unsigned)g) ^ sw));
#pragma unroll
          for (int lt = 0; lt < 2; ++lt) {
            float4v c = (float4v)(0.0f);
            c = __builtin_amdgcn_mfma_f32_16x16x32_bf16(kf0, qf[j][lt][0], c, 0, 0, 0);
            c = __builtin_amdgcn_mfma_f32_16x16x32_bf16(kf1, qf[j][lt][1], c, 0, 0, 0);
            sc[j][lt][ss] = c;
          }
        }
      }

      // exp (own 2 n) + per-lane partial sums over j; bf16-pack, exchange with
      // partner wave (other 2 n). exp2 unclamped (overflow needs 88 sigma);
      // eps in the denominator bounds inv.
      float ex[2][2][2][4];  // [j][lt][ss][r]
      float4v ps[2][2];      // [lt][ss]
#pragma unroll
      for (int lt = 0; lt < 2; ++lt)
#pragma unroll
        for (int ss = 0; ss < 2; ++ss) {
#pragma unroll
          for (int j = 0; j < 2; ++j)
#pragma unroll
            for (int r = 0; r < 4; ++r)
              ex[j][lt][ss][r] = EXP2(sc[j][lt][ss][r]);
#pragma unroll
          for (int r = 0; r < 4; ++r)
            ps[lt][ss][r] = ex[0][lt][ss][r] + ex[1][lt][ss][r];
          *(short4v*)(exW + (lt * 2 + ss) * 8) =
              pack4(ps[lt][ss][0], ps[lt][ss][1], ps[lt][ss][2], ps[lt][ss][3]);
        }
      __builtin_amdgcn_s_barrier();   // exchange visible (non-draining)

      short8 pf8[2][2];  // [j][lt]: B-frag slot i -> s = 4g + (i&3) + 16*(i>>2)
#pragma unroll
      for (int lt = 0; lt < 2; ++lt) {
#pragma unroll
        for (int ss = 0; ss < 2; ++ss) {
          short4v po = *(const short4v*)(exR + (lt * 2 + ss) * 8);
#pragma unroll
          for (int r = 0; r < 4; ++r) {
            float inv = __builtin_amdgcn_rcpf(
                ps[lt][ss][r] + bf2f((unsigned short)po[r]) + 1e-30f);
            ex[0][lt][ss][r] *= inv;
            ex[1][lt][ss][r] *= inv;
          }
        }
#pragma unroll
        for (int j = 0; j < 2; ++j) {
          float4v e0 = {ex[j][lt][0][0], ex[j][lt][0][1], ex[j][lt][0][2], ex[j][lt][0][3]};
          float4v e1 = {ex[j][lt][1][0], ex[j][lt][1][1], ex[j][lt][1][2], ex[j][lt][1][3]};
          pf8[j][lt] = pack8(e0, e1);
        }
      }

      // PV full-K (16x16x32): V-frag (one b128) reused across both l-subtiles.
#pragma unroll
      for (int j = 0; j < 2; ++j) {
        char* vn = vbase + (n0 + j) * 4096;
#pragma unroll
        for (int t4 = 0; t4 < 4; ++t4) {
          short8 va = *(const short8*)(vn + (t4 * 16 + rl) * 64 + voffr);
#pragma unroll
          for (int lt = 0; lt < 2; ++lt)
            ha[j][lt][t4] = __builtin_amdgcn_mfma_f32_16x16x32_bf16(va, pf8[j][lt], ha[j][lt][t4], 0, 0, 0);
        }
      }

      if (t + 3 < 64) stage(t + 3, (ti + 3) & 3);
      asm volatile("s_waitcnt vmcnt(8)" ::: "memory");
      __builtin_amdgcn_s_barrier();
    }
  }

  // epilogue: heads^T C-frag -> heads[n*2048+l][h*64+dk] bf16, 8B stores
#pragma unroll
  for (int j = 0; j < 2; ++j)
#pragma unroll
    for (int lt = 0; lt < 2; ++lt)
#pragma unroll
      for (int tt = 0; tt < 4; ++tt) {
        short4v w = pack4(ha[j][lt][tt][0], ha[j][lt][tt][1], ha[j][lt][tt][2], ha[j][lt][tt][3]);
        size_t off = (size_t)((n0 + j) * 2048 + l0 + lt * 16 + rl) * 1024
                   + h * 64 + tt * 16 + 4 * g;
        *(short4v*)(hb + off) = w;
      }
}

extern "C" void kernel_launch(void* const* d_in, const int* in_sizes, int n_in,
                              void* d_out, int out_size, void* d_ws, size_t ws_size,
                              hipStream_t stream)
{
  const float* Q  = (const float*)d_in[0];
  const float* K  = (const float*)d_in[1];
  const float* V  = (const float*)d_in[2];
  const float* Wq = (const float*)d_in[3];
  const float* Wo = (const float*)d_in[4];

  unsigned short* qb  = (unsigned short*)d_ws;            // 16 MB each
  unsigned short* kw  = qb + (size_t)8192 * 1024;
  unsigned short* vt  = kw + (size_t)8192 * 1024;         // v^T (s-permuted)
  unsigned short* wqb = vt + (size_t)8192 * 1024;         // Wq bf16, 2 MB
  unsigned short* wob = wqb + (size_t)1024 * 1024;        // Wo bf16, 2 MB
  unsigned short* hw  = qb;  // heads alias q (wave-exclusive read-then-write)

  const float CS = 0.18033688011112042f;  // log2(e)/8: folds 1/sqrt(dk) + ln2 into q

  dim3 gg(64, 8), bb(256);
  cvt_bf16<<<512, 256, 0, stream>>>(Wq, wqb, 131072);
  cvt_bf16<<<512, 256, 0, stream>>>(Wo, wob, 131072);
  gemm_bt128<1, 0><<<gg, bb, 0, stream>>>(Q, wqb, qb, 8192, 1024, 1024, CS);
  gemm_bt128<1, 0><<<gg, bb, 0, stream>>>(K, wqb, kw, 8192, 1024, 1024, 1.0f);
  gemm_bt128<1, 2><<<gg, bb, 0, stream>>>(V, wqb, vt, 8192, 1024, 1024, 1.0f);
  attn_bn<<<dim3(16, 16), dim3(512), 0, stream>>>(qb, kw, vt, hw);
  gemm_bt128<0, 1><<<gg, bb, 0, stream>>>(hw, wob, (float*)d_out, 8192, 1024, 1024, 1.0f);
}

// Round 20
// 238.382 us; speedup vs baseline: 1.0451x; 1.0451x over previous
//
#include <hip/hip_runtime.h>
#include <hip/hip_bf16.h>

typedef __attribute__((ext_vector_type(8))) short short8;
typedef __attribute__((ext_vector_type(4))) short short4v;
typedef __attribute__((ext_vector_type(4))) float float4v;

#define DEVI static __device__ __forceinline__

#if __has_builtin(__builtin_amdgcn_exp2f)
#define EXP2(x) __builtin_amdgcn_exp2f(x)
#else
#define EXP2(x) exp2f(x)
#endif

DEVI unsigned short f2bf(float f) {
  unsigned int u = __builtin_bit_cast(unsigned int, f);
  u += 0x7fffu + ((u >> 16) & 1u);
  return (unsigned short)(u >> 16);
}

// vendor-emitted packed f32->bf16 (v_cvt_pk_bf16_f32); NEVER hand-rolled asm (r5/r6 NaN)
DEVI short8 pack8(float4v a, float4v b) {  // elems 0..3 <- a, 4..7 <- b
  struct P4 { __hip_bfloat162 x, y, z, w; } t;
  t.x = __float22bfloat162_rn(make_float2(a[0], a[1]));
  t.y = __float22bfloat162_rn(make_float2(a[2], a[3]));
  t.z = __float22bfloat162_rn(make_float2(b[0], b[1]));
  t.w = __float22bfloat162_rn(make_float2(b[2], b[3]));
  short8 r;
  __builtin_memcpy(&r, &t, 16);
  return r;
}

DEVI short4v pack4(float a, float b, float c, float d) {
  struct P2 { __hip_bfloat162 x, y; } t;
  t.x = __float22bfloat162_rn(make_float2(a, b));
  t.y = __float22bfloat162_rn(make_float2(c, d));
  short4v r;
  __builtin_memcpy(&r, &t, 8);
  return r;
}

DEVI void gload16(const void* src, void* lds_dst) {
  __builtin_amdgcn_global_load_lds(
      (const __attribute__((address_space(1))) void*)src,
      (__attribute__((address_space(3))) void*)lds_dst, 16, 0, 0);
}

// f32 -> bf16 for BOTH weight matrices in one dispatch (grid 1024 x 256)
__global__ __launch_bounds__(256)
void cvt_bf16_2(const float* __restrict__ a, const float* __restrict__ b,
                unsigned short* __restrict__ oa, unsigned short* __restrict__ ob)
{
  int i = blockIdx.x * 256 + threadIdx.x;       // 0 .. 262143
  const float* src = (i < 131072) ? a : b;
  unsigned short* dst = (i < 131072) ? oa : ob;
  int j = (i < 131072) ? i : i - 131072;
  float4v x = *(const float4v*)(src + (size_t)j * 8);
  float4v y = *(const float4v*)(src + (size_t)j * 8 + 4);
  *(short8*)(dst + (size_t)j * 8) = pack8(x, y);
}

// FUSED projection GEMMs: C = X * Wq^T for X in {Q, K, V} in ONE dispatch.
// Grid (192, 8): sel = bx>>6 picks source/dest/epilogue (block-uniform).
//   sel 0: Q -> qb, bf16 row-major, scaled by CS.
//   sel 1: K -> kw, bf16 row-major.
//   sel 2: V -> vt, bf16 TRANSPOSED CT[1024][8192], m permuted in 32-blocks
//          (32q+16h'+4c'+i -> 32q+8c'+4h'+i) for the attn PV b128 read.
// A f32 reg-staged+converted into padded-row LDS; B bf16 via gload16 (r18 path).
__global__ __launch_bounds__(256, 2)
void gemm_proj3(const float* __restrict__ Qp, const float* __restrict__ Kp,
                const float* __restrict__ Vp, const unsigned short* __restrict__ Bp,
                unsigned short* __restrict__ qb, unsigned short* __restrict__ kw,
                unsigned short* __restrict__ vt, float CS)
{
  constexpr int Kd = 1024, Nc = 1024, M = 8192;
  __shared__ alignas(16) short As[2][128 * 40];
  __shared__ alignas(16) short Bs[2][128 * 32];

  const int sel = blockIdx.x >> 6;
  const float* Af = (sel == 0) ? Qp : (sel == 1) ? Kp : Vp;
  unsigned short* Cp = (sel == 0) ? qb : (sel == 1) ? kw : vt;
  const float oscale = (sel == 0) ? CS : 1.0f;

  const int tid = threadIdx.x;
  const int lane = tid & 63;
  const int wid = tid >> 6;
  const int rl = lane & 15;
  const int g = lane >> 4;
  const int bm = (blockIdx.x & 63) * 128;
  const int bn = blockIdx.y * 128;
  const int wm = (wid >> 1) * 64;
  const int wn = (wid & 1) * 64;
  const int srow = tid >> 1;
  const int k0 = (tid & 1) * 16;

  float4v acc[4][4];
#pragma unroll
  for (int i = 0; i < 4; ++i)
#pragma unroll
    for (int j = 0; j < 4; ++j) acc[i][j] = (float4v)(0.0f);

  float4v afr[4];
  const int NK = Kd >> 5;
  const int grow = tid >> 2;
  const int gchk = tid & 3;

  auto stageB = [&](int ks, int b) {
#pragma unroll
    for (int j = 0; j < 2; ++j) {
      const unsigned short* src = Bp + (size_t)(bn + grow + j * 64) * Kd + ks * 32 + gchk * 8;
      gload16(src, (char*)Bs[b] + j * 4096 + wid * 1024);
    }
  };
  auto loadA = [&](int ks) {
    size_t base = (size_t)(bm + srow) * Kd + ks * 32 + k0;
    afr[0] = *(const float4v*)(Af + base);
    afr[1] = *(const float4v*)(Af + base + 4);
    afr[2] = *(const float4v*)(Af + base + 8);
    afr[3] = *(const float4v*)(Af + base + 12);
  };
  auto packWriteA = [&](int b) {
    *(short8*)(As[b] + srow * 40 + k0)     = pack8(afr[0], afr[1]);
    *(short8*)(As[b] + srow * 40 + k0 + 8) = pack8(afr[2], afr[3]);
  };

  stageB(0, 0);
  loadA(0);
  packWriteA(0);
  __syncthreads();

  for (int ks = 0; ks < NK; ++ks) {
    const int b = ks & 1;
    if (ks + 1 < NK) {
      stageB(ks + 1, b ^ 1);
      loadA(ks + 1);
    }

    short8 a8[4], b8[4];
#pragma unroll
    for (int mt = 0; mt < 4; ++mt)
      a8[mt] = *(const short8*)(As[b] + (wm + mt * 16 + rl) * 40 + 8 * g);
#pragma unroll
    for (int nt = 0; nt < 4; ++nt)
      b8[nt] = *(const short8*)(Bs[b] + (wn + nt * 16 + rl) * 32 + 8 * g);
#pragma unroll
    for (int mt = 0; mt < 4; ++mt)
#pragma unroll
      for (int nt = 0; nt < 4; ++nt)
        acc[mt][nt] = __builtin_amdgcn_mfma_f32_16x16x32_bf16(a8[mt], b8[nt], acc[mt][nt], 0, 0, 0);

    if (ks + 1 < NK) packWriteA(b ^ 1);
    __syncthreads();
  }

  if (sel != 2) {
#pragma unroll
    for (int mt = 0; mt < 4; ++mt)
#pragma unroll
      for (int nt = 0; nt < 4; ++nt) {
        const int col = bn + wn + nt * 16 + rl;
        const int row0 = bm + wm + mt * 16 + 4 * g;
#pragma unroll
        for (int r = 0; r < 4; ++r)
          Cp[(size_t)(row0 + r) * Nc + col] = f2bf(acc[mt][nt][r] * oscale);
      }
  } else {
#pragma unroll
    for (int mt = 0; mt < 4; ++mt)
#pragma unroll
      for (int nt = 0; nt < 4; ++nt) {
        const int col = bn + wn + nt * 16 + rl;
        const int row0 = bm + wm + mt * 16 + 4 * g;
        short4v w = pack4(acc[mt][nt][0], acc[mt][nt][1], acc[mt][nt][2], acc[mt][nt][3]);
        const int u = row0 & 31;      // row0 multiple of 4: u = 16h' + 4c'
        const int pm = (row0 & ~31) | (((u >> 2) & 3) << 3) | (((u >> 4) & 1) << 2);
        *(short4v*)(Cp + (size_t)col * M + pm) = w;
      }
  }
}

// Final GEMM: C_f32 = A_bf16 * B_bf16^T, both staged via gload16 (m97 path).
__global__ __launch_bounds__(256, 2)
void gemm_out(const unsigned short* __restrict__ Ab, const unsigned short* __restrict__ Bp,
              float* __restrict__ Cp, int M, int Nc, int Kd)
{
  __shared__ alignas(16) short As[2][128 * 32];
  __shared__ alignas(16) short Bs[2][128 * 32];

  const int tid = threadIdx.x;
  const int lane = tid & 63;
  const int wid = tid >> 6;
  const int rl = lane & 15;
  const int g = lane >> 4;
  const int bm = blockIdx.x * 128;
  const int bn = blockIdx.y * 128;
  const int wm = (wid >> 1) * 64;
  const int wn = (wid & 1) * 64;

  float4v acc[4][4];
#pragma unroll
  for (int i = 0; i < 4; ++i)
#pragma unroll
    for (int j = 0; j < 4; ++j) acc[i][j] = (float4v)(0.0f);

  const int NK = Kd >> 5;
  const int grow = tid >> 2;
  const int gchk = tid & 3;

  auto stageAB = [&](int ks, int b) {
#pragma unroll
    for (int j = 0; j < 2; ++j) {
      const unsigned short* sa = Ab + (size_t)(bm + grow + j * 64) * Kd + ks * 32 + gchk * 8;
      gload16(sa, (char*)As[b] + j * 4096 + wid * 1024);
      const unsigned short* sb = Bp + (size_t)(bn + grow + j * 64) * Kd + ks * 32 + gchk * 8;
      gload16(sb, (char*)Bs[b] + j * 4096 + wid * 1024);
    }
  };

  stageAB(0, 0);
  __syncthreads();

  for (int ks = 0; ks < NK; ++ks) {
    const int b = ks & 1;
    if (ks + 1 < NK) stageAB(ks + 1, b ^ 1);

    short8 a8[4], b8[4];
#pragma unroll
    for (int mt = 0; mt < 4; ++mt)
      a8[mt] = *(const short8*)(As[b] + (wm + mt * 16 + rl) * 32 + 8 * g);
#pragma unroll
    for (int nt = 0; nt < 4; ++nt)
      b8[nt] = *(const short8*)(Bs[b] + (wn + nt * 16 + rl) * 32 + 8 * g);
#pragma unroll
    for (int mt = 0; mt < 4; ++mt)
#pragma unroll
      for (int nt = 0; nt < 4; ++nt)
        acc[mt][nt] = __builtin_amdgcn_mfma_f32_16x16x32_bf16(a8[mt], b8[nt], acc[mt][nt], 0, 0, 0);

    __syncthreads();
  }

#pragma unroll
  for (int mt = 0; mt < 4; ++mt)
#pragma unroll
    for (int nt = 0; nt < 4; ++nt) {
      const int col = bn + wn + nt * 16 + rl;
      const int row0 = bm + wm + mt * 16 + 4 * g;
#pragma unroll
      for (int r = 0; r < 4; ++r)
        Cp[(size_t)(row0 + r) * Nc + col] = acc[mt][nt][r];
    }
}

// Fused attention, softmax over the batch axis n (size 4).  [r18 structure, verbatim]
// Grid: (L/128, H) = (16,16). 512 threads = 8 waves; wave w owns 16 l-rows, all 4 n.
// qb: bf16 [n*2048+l][1024], PRE-SCALED by log2(e)/8. kb: bf16 [n*2048+s][1024].
// vtb: bf16 TRANSPOSED+PERMUTED [h*64+dk][perm(n*2048+s)]. hb may alias qb.
// LDS: FOUR 32KB buffers (counted-vmcnt pipeline, 3 stages in flight):
//   K: 4n x [32 s][128B], 16B chunk c holds global chunk c^(s&7).
//   V^T: 4n x [64 dk][64B]; data chunk c at phys chunk c^((dk>>1)&3).
// PV full-K 16x16x32: one b128 A-read + one MFMA per (n,t4); P B-frag = pack8
// of both ss-halves (slot bijection s = 4g+(i&3)+16(i>>2), HW-verified r11/r17).
__global__ __launch_bounds__(512, 2)
void attn_bn(const unsigned short* __restrict__ qb,
             const unsigned short* __restrict__ kb,
             const unsigned short* __restrict__ vtb,
             unsigned short* __restrict__ hb)
{
  __shared__ alignas(128) char smem[131072];

  const int tid = threadIdx.x;
  const int lane = tid & 63;
  const int wid = tid >> 6;          // 0..7
  const int rl = lane & 15;
  const int g = lane >> 4;
  const int h = blockIdx.y;
  const int l0 = blockIdx.x * 128 + wid * 16;

  short8 qf[4][2];
#pragma unroll
  for (int n = 0; n < 4; ++n)
#pragma unroll
    for (int dh = 0; dh < 2; ++dh)
      qf[n][dh] = *(const short8*)(qb + (size_t)(n * 2048 + l0 + rl) * 1024 + h * 64 + dh * 32 + 8 * g);

  float4v ha[4][4];
#pragma unroll
  for (int n = 0; n < 4; ++n)
#pragma unroll
    for (int t = 0; t < 4; ++t) ha[n][t] = (float4v)(0.0f);

  const size_t koff0 = ((size_t)(wid * 2048) + (size_t)(lane >> 3)) * 1024
                     + (size_t)(h * 64) + (size_t)(((lane & 7) ^ (lane >> 3)) * 8);
  const size_t voff0 = ((size_t)(h * 64) + (size_t)(lane >> 2)) * 8192
                     + (size_t)((wid - 4) * 2048)
                     + (size_t)((((lane & 3) ^ ((lane >> 3) & 3)) * 8));

  auto stage = [&](int step, int b) {
    if (wid < 4) {
      char* kdst = smem + b * 32768 + wid * 4096;
      const unsigned short* ksrc = kb + koff0 + (size_t)step * 32 * 1024;
#pragma unroll
      for (int ii = 0; ii < 4; ++ii)
        gload16(ksrc + ii * 8192, kdst + ii * 1024);
    } else {
      char* vdst = smem + b * 32768 + 16384 + (wid - 4) * 4096;
      const unsigned short* vsrc = vtb + voff0 + (size_t)step * 32;
#pragma unroll
      for (int ii = 0; ii < 4; ++ii)
        gload16(vsrc + (size_t)ii * 16 * 8192, vdst + ii * 1024);
    }
  };

  stage(0, 0);
  stage(1, 1);
  stage(2, 2);
  asm volatile("s_waitcnt vmcnt(8)" ::: "memory");
  __builtin_amdgcn_s_barrier();

  const unsigned voffr = ((unsigned)(g ^ ((rl >> 1) & 3))) << 4;

  for (int to = 0; to < 16; ++to) {
#pragma unroll
    for (int ti = 0; ti < 4; ++ti) {
      const int t = to * 4 + ti;
      char* kbase = smem + ti * 32768;
      char* vbase = kbase + 16384;

      float4v sc[4][2];
#pragma unroll
      for (int n = 0; n < 4; ++n) {
        char* kn = kbase + n * 4096;
#pragma unroll
        for (int ss = 0; ss < 2; ++ss) {
          const int srw = ss * 16 + rl;
          const unsigned sw = ((unsigned)(srw & 7)) << 4;
          short8 kf0 = *(const short8*)(kn + srw * 128 + ((16u * (unsigned)g) ^ sw));
          short8 kf1 = *(const short8*)(kn + srw * 128 + ((64u + 16u * (unsigned)g) ^ sw));
          float4v c = (float4v)(0.0f);
          c = __builtin_amdgcn_mfma_f32_16x16x32_bf16(kf0, qf[n][0], c, 0, 0, 0);
          c = __builtin_amdgcn_mfma_f32_16x16x32_bf16(kf1, qf[n][1], c, 0, 0, 0);
          sc[n][ss] = c;
        }
      }

      float ex[4][2][4];
#pragma unroll
      for (int ss = 0; ss < 2; ++ss) {
#pragma unroll
        for (int n = 0; n < 4; ++n)
#pragma unroll
          for (int r = 0; r < 4; ++r)
            ex[n][ss][r] = EXP2(sc[n][ss][r]);
#pragma unroll
        for (int r = 0; r < 4; ++r) {
          float inv = __builtin_amdgcn_rcpf((ex[0][ss][r] + ex[1][ss][r])
                                          + (ex[2][ss][r] + ex[3][ss][r]) + 1e-30f);
          ex[0][ss][r] *= inv; ex[1][ss][r] *= inv;
          ex[2][ss][r] *= inv; ex[3][ss][r] *= inv;
        }
      }
      short8 pf8[4];
#pragma unroll
      for (int n = 0; n < 4; ++n) {
        float4v e0 = {ex[n][0][0], ex[n][0][1], ex[n][0][2], ex[n][0][3]};
        float4v e1 = {ex[n][1][0], ex[n][1][1], ex[n][1][2], ex[n][1][3]};
        pf8[n] = pack8(e0, e1);
      }

#pragma unroll
      for (int n = 0; n < 4; ++n) {
        char* vn = vbase + n * 4096;
#pragma unroll
        for (int t4 = 0; t4 < 4; ++t4) {
          short8 va = *(const short8*)(vn + (t4 * 16 + rl) * 64 + voffr);
          ha[n][t4] = __builtin_amdgcn_mfma_f32_16x16x32_bf16(va, pf8[n], ha[n][t4], 0, 0, 0);
        }
      }

      if (t + 3 < 64) stage(t + 3, (ti + 3) & 3);
      asm volatile("s_waitcnt vmcnt(8)" ::: "memory");
      __builtin_amdgcn_s_barrier();
    }
  }

#pragma unroll
  for (int n = 0; n < 4; ++n)
#pragma unroll
    for (int tt = 0; tt < 4; ++tt) {
      short4v w = pack4(ha[n][tt][0], ha[n][tt][1], ha[n][tt][2], ha[n][tt][3]);
      size_t off = (size_t)(n * 2048 + l0 + rl) * 1024 + h * 64 + tt * 16 + 4 * g;
      *(short4v*)(hb + off) = w;
    }
}

extern "C" void kernel_launch(void* const* d_in, const int* in_sizes, int n_in,
                              void* d_out, int out_size, void* d_ws, size_t ws_size,
                              hipStream_t stream)
{
  const float* Q  = (const float*)d_in[0];
  const float* K  = (const float*)d_in[1];
  const float* V  = (const float*)d_in[2];
  const float* Wq = (const float*)d_in[3];
  const float* Wo = (const float*)d_in[4];

  unsigned short* qb  = (unsigned short*)d_ws;            // 16 MB each
  unsigned short* kw  = qb + (size_t)8192 * 1024;
  unsigned short* vt  = kw + (size_t)8192 * 1024;         // v^T (s-permuted)
  unsigned short* wqb = vt + (size_t)8192 * 1024;         // Wq bf16, 2 MB
  unsigned short* wob = wqb + (size_t)1024 * 1024;        // Wo bf16, 2 MB
  unsigned short* hw  = qb;  // heads alias q (block-exclusive read-then-write)

  const float CS = 0.18033688011112042f;  // log2(e)/8: folds 1/sqrt(dk) + ln2 into q

  cvt_bf16_2<<<1024, 256, 0, stream>>>(Wq, Wo, wqb, wob);
  gemm_proj3<<<dim3(192, 8), dim3(256), 0, stream>>>(Q, K, V, wqb, qb, kw, vt, CS);
  attn_bn<<<dim3(16, 16), dim3(512), 0, stream>>>(qb, kw, vt, hw);
  gemm_out<<<dim3(64, 8), dim3(256), 0, stream>>>(hw, wob, (float*)d_out, 8192, 1024, 1024);
}

// Round 21
// 225.277 us; speedup vs baseline: 1.1059x; 1.0582x over previous
//
#include <hip/hip_runtime.h>
#include <hip/hip_bf16.h>

typedef __attribute__((ext_vector_type(8))) short short8;
typedef __attribute__((ext_vector_type(4))) short short4v;
typedef __attribute__((ext_vector_type(4))) float float4v;

#define DEVI static __device__ __forceinline__

#if __has_builtin(__builtin_amdgcn_exp2f)
#define EXP2(x) __builtin_amdgcn_exp2f(x)
#else
#define EXP2(x) exp2f(x)
#endif

DEVI unsigned short f2bf(float f) {
  unsigned int u = __builtin_bit_cast(unsigned int, f);
  u += 0x7fffu + ((u >> 16) & 1u);
  return (unsigned short)(u >> 16);
}

// vendor-emitted packed f32->bf16 (v_cvt_pk_bf16_f32); NEVER hand-rolled asm (r5/r6 NaN)
DEVI short8 pack8(float4v a, float4v b) {  // elems 0..3 <- a, 4..7 <- b
  struct P4 { __hip_bfloat162 x, y, z, w; } t;
  t.x = __float22bfloat162_rn(make_float2(a[0], a[1]));
  t.y = __float22bfloat162_rn(make_float2(a[2], a[3]));
  t.z = __float22bfloat162_rn(make_float2(b[0], b[1]));
  t.w = __float22bfloat162_rn(make_float2(b[2], b[3]));
  short8 r;
  __builtin_memcpy(&r, &t, 16);
  return r;
}

DEVI short4v pack4(float a, float b, float c, float d) {
  struct P2 { __hip_bfloat162 x, y; } t;
  t.x = __float22bfloat162_rn(make_float2(a, b));
  t.y = __float22bfloat162_rn(make_float2(c, d));
  short4v r;
  __builtin_memcpy(&r, &t, 8);
  return r;
}

DEVI void gload16(const void* src, void* lds_dst) {
  __builtin_amdgcn_global_load_lds(
      (const __attribute__((address_space(1))) void*)src,
      (__attribute__((address_space(3))) void*)lds_dst, 16, 0, 0);
}

// f32 -> bf16 for BOTH weight matrices in one dispatch (grid 1024 x 256)
__global__ __launch_bounds__(256)
void cvt_bf16_2(const float* __restrict__ a, const float* __restrict__ b,
                unsigned short* __restrict__ oa, unsigned short* __restrict__ ob)
{
  int i = blockIdx.x * 256 + threadIdx.x;       // 0 .. 262143
  const float* src = (i < 131072) ? a : b;
  unsigned short* dst = (i < 131072) ? oa : ob;
  int j = (i < 131072) ? i : i - 131072;
  float4v x = *(const float4v*)(src + (size_t)j * 8);
  float4v y = *(const float4v*)(src + (size_t)j * 8 + 4);
  *(short8*)(dst + (size_t)j * 8) = pack8(x, y);
}

// FUSED projection GEMMs: C = X * Wq^T for X in {Q, K, V} in ONE dispatch.
// Grid (64, 24): sel = by>>3 (dispatch is x-major -> co-resident blocks share
// one sel -> one A-stream per XCD L2 at a time; r20's sel-by-x mixed all three
// and overfetched 50%).  bn = (by&7)*128, bm = bx*128.
//   sel 0: Q -> qb, bf16 row-major, scaled by CS.
//   sel 1: K -> kw, bf16 row-major.
//   sel 2: V -> vt, bf16 TRANSPOSED CT[1024][8192], m permuted in 32-blocks
//          (32q+16h'+4c'+i -> 32q+8c'+4h'+i) for the attn PV b128 read.
// A f32 reg-staged+converted into padded-row LDS; B bf16 via gload16 (r18 path).
__global__ __launch_bounds__(256, 2)
void gemm_proj3(const float* __restrict__ Qp, const float* __restrict__ Kp,
                const float* __restrict__ Vp, const unsigned short* __restrict__ Bp,
                unsigned short* __restrict__ qb, unsigned short* __restrict__ kw,
                unsigned short* __restrict__ vt, float CS)
{
  constexpr int Kd = 1024, Nc = 1024, M = 8192;
  __shared__ alignas(16) short As[2][128 * 40];
  __shared__ alignas(16) short Bs[2][128 * 32];

  const int sel = blockIdx.y >> 3;
  const float* Af = (sel == 0) ? Qp : (sel == 1) ? Kp : Vp;
  unsigned short* Cp = (sel == 0) ? qb : (sel == 1) ? kw : vt;
  const float oscale = (sel == 0) ? CS : 1.0f;

  const int tid = threadIdx.x;
  const int lane = tid & 63;
  const int wid = tid >> 6;
  const int rl = lane & 15;
  const int g = lane >> 4;
  const int bm = blockIdx.x * 128;
  const int bn = (blockIdx.y & 7) * 128;
  const int wm = (wid >> 1) * 64;
  const int wn = (wid & 1) * 64;
  const int srow = tid >> 1;
  const int k0 = (tid & 1) * 16;

  float4v acc[4][4];
#pragma unroll
  for (int i = 0; i < 4; ++i)
#pragma unroll
    for (int j = 0; j < 4; ++j) acc[i][j] = (float4v)(0.0f);

  float4v afr[4];
  const int NK = Kd >> 5;
  const int grow = tid >> 2;
  const int gchk = tid & 3;

  auto stageB = [&](int ks, int b) {
#pragma unroll
    for (int j = 0; j < 2; ++j) {
      const unsigned short* src = Bp + (size_t)(bn + grow + j * 64) * Kd + ks * 32 + gchk * 8;
      gload16(src, (char*)Bs[b] + j * 4096 + wid * 1024);
    }
  };
  auto loadA = [&](int ks) {
    size_t base = (size_t)(bm + srow) * Kd + ks * 32 + k0;
    afr[0] = *(const float4v*)(Af + base);
    afr[1] = *(const float4v*)(Af + base + 4);
    afr[2] = *(const float4v*)(Af + base + 8);
    afr[3] = *(const float4v*)(Af + base + 12);
  };
  auto packWriteA = [&](int b) {
    *(short8*)(As[b] + srow * 40 + k0)     = pack8(afr[0], afr[1]);
    *(short8*)(As[b] + srow * 40 + k0 + 8) = pack8(afr[2], afr[3]);
  };

  stageB(0, 0);
  loadA(0);
  packWriteA(0);
  __syncthreads();

  for (int ks = 0; ks < NK; ++ks) {
    const int b = ks & 1;
    if (ks + 1 < NK) {
      stageB(ks + 1, b ^ 1);
      loadA(ks + 1);
    }

    short8 a8[4], b8[4];
#pragma unroll
    for (int mt = 0; mt < 4; ++mt)
      a8[mt] = *(const short8*)(As[b] + (wm + mt * 16 + rl) * 40 + 8 * g);
#pragma unroll
    for (int nt = 0; nt < 4; ++nt)
      b8[nt] = *(const short8*)(Bs[b] + (wn + nt * 16 + rl) * 32 + 8 * g);
#pragma unroll
    for (int mt = 0; mt < 4; ++mt)
#pragma unroll
      for (int nt = 0; nt < 4; ++nt)
        acc[mt][nt] = __builtin_amdgcn_mfma_f32_16x16x32_bf16(a8[mt], b8[nt], acc[mt][nt], 0, 0, 0);

    if (ks + 1 < NK) packWriteA(b ^ 1);
    __syncthreads();
  }

  if (sel != 2) {
#pragma unroll
    for (int mt = 0; mt < 4; ++mt)
#pragma unroll
      for (int nt = 0; nt < 4; ++nt) {
        const int col = bn + wn + nt * 16 + rl;
        const int row0 = bm + wm + mt * 16 + 4 * g;
#pragma unroll
        for (int r = 0; r < 4; ++r)
          Cp[(size_t)(row0 + r) * Nc + col] = f2bf(acc[mt][nt][r] * oscale);
      }
  } else {
#pragma unroll
    for (int mt = 0; mt < 4; ++mt)
#pragma unroll
      for (int nt = 0; nt < 4; ++nt) {
        const int col = bn + wn + nt * 16 + rl;
        const int row0 = bm + wm + mt * 16 + 4 * g;
        short4v w = pack4(acc[mt][nt][0], acc[mt][nt][1], acc[mt][nt][2], acc[mt][nt][3]);
        const int u = row0 & 31;      // row0 multiple of 4: u = 16h' + 4c'
        const int pm = (row0 & ~31) | (((u >> 2) & 3) << 3) | (((u >> 4) & 1) << 2);
        *(short4v*)(Cp + (size_t)col * M + pm) = w;
      }
  }
}

// Final GEMM: C_f32 = A_bf16 * B_bf16^T, both staged via gload16 (m97 path).
__global__ __launch_bounds__(256, 2)
void gemm_out(const unsigned short* __restrict__ Ab, const unsigned short* __restrict__ Bp,
              float* __restrict__ Cp, int M, int Nc, int Kd)
{
  __shared__ alignas(16) short As[2][128 * 32];
  __shared__ alignas(16) short Bs[2][128 * 32];

  const int tid = threadIdx.x;
  const int lane = tid & 63;
  const int wid = tid >> 6;
  const int rl = lane & 15;
  const int g = lane >> 4;
  const int bm = blockIdx.x * 128;
  const int bn = blockIdx.y * 128;
  const int wm = (wid >> 1) * 64;
  const int wn = (wid & 1) * 64;

  float4v acc[4][4];
#pragma unroll
  for (int i = 0; i < 4; ++i)
#pragma unroll
    for (int j = 0; j < 4; ++j) acc[i][j] = (float4v)(0.0f);

  const int NK = Kd >> 5;
  const int grow = tid >> 2;
  const int gchk = tid & 3;

  auto stageAB = [&](int ks, int b) {
#pragma unroll
    for (int j = 0; j < 2; ++j) {
      const unsigned short* sa = Ab + (size_t)(bm + grow + j * 64) * Kd + ks * 32 + gchk * 8;
      gload16(sa, (char*)As[b] + j * 4096 + wid * 1024);
      const unsigned short* sb = Bp + (size_t)(bn + grow + j * 64) * Kd + ks * 32 + gchk * 8;
      gload16(sb, (char*)Bs[b] + j * 4096 + wid * 1024);
    }
  };

  stageAB(0, 0);
  __syncthreads();

  for (int ks = 0; ks < NK; ++ks) {
    const int b = ks & 1;
    if (ks + 1 < NK) stageAB(ks + 1, b ^ 1);

    short8 a8[4], b8[4];
#pragma unroll
    for (int mt = 0; mt < 4; ++mt)
      a8[mt] = *(const short8*)(As[b] + (wm + mt * 16 + rl) * 32 + 8 * g);
#pragma unroll
    for (int nt = 0; nt < 4; ++nt)
      b8[nt] = *(const short8*)(Bs[b] + (wn + nt * 16 + rl) * 32 + 8 * g);
#pragma unroll
    for (int mt = 0; mt < 4; ++mt)
#pragma unroll
      for (int nt = 0; nt < 4; ++nt)
        acc[mt][nt] = __builtin_amdgcn_mfma_f32_16x16x32_bf16(a8[mt], b8[nt], acc[mt][nt], 0, 0, 0);

    __syncthreads();
  }

#pragma unroll
  for (int mt = 0; mt < 4; ++mt)
#pragma unroll
    for (int nt = 0; nt < 4; ++nt) {
      const int col = bn + wn + nt * 16 + rl;
      const int row0 = bm + wm + mt * 16 + 4 * g;
#pragma unroll
      for (int r = 0; r < 4; ++r)
        Cp[(size_t)(row0 + r) * Nc + col] = acc[mt][nt][r];
    }
}

// Fused attention, softmax over the batch axis n (size 4).  [r18 structure +
// T5 setprio around the MFMA clusters]
// Grid: (L/128, H) = (16,16). 512 threads = 8 waves; wave w owns 16 l-rows, all 4 n.
// qb: bf16 [n*2048+l][1024], PRE-SCALED by log2(e)/8. kb: bf16 [n*2048+s][1024].
// vtb: bf16 TRANSPOSED+PERMUTED [h*64+dk][perm(n*2048+s)]. hb may alias qb.
// LDS: FOUR 32KB buffers (counted-vmcnt pipeline, 3 stages in flight):
//   K: 4n x [32 s][128B], 16B chunk c holds global chunk c^(s&7).
//   V^T: 4n x [64 dk][64B]; data chunk c at phys chunk c^((dk>>1)&3).
// PV full-K 16x16x32: one b128 A-read + one MFMA per (n,t4); P B-frag = pack8
// of both ss-halves (slot bijection s = 4g+(i&3)+16(i>>2), HW-verified r11/r17).
__global__ __launch_bounds__(512, 2)
void attn_bn(const unsigned short* __restrict__ qb,
             const unsigned short* __restrict__ kb,
             const unsigned short* __restrict__ vtb,
             unsigned short* __restrict__ hb)
{
  __shared__ alignas(128) char smem[131072];

  const int tid = threadIdx.x;
  const int lane = tid & 63;
  const int wid = tid >> 6;          // 0..7
  const int rl = lane & 15;
  const int g = lane >> 4;
  const int h = blockIdx.y;
  const int l0 = blockIdx.x * 128 + wid * 16;

  short8 qf[4][2];
#pragma unroll
  for (int n = 0; n < 4; ++n)
#pragma unroll
    for (int dh = 0; dh < 2; ++dh)
      qf[n][dh] = *(const short8*)(qb + (size_t)(n * 2048 + l0 + rl) * 1024 + h * 64 + dh * 32 + 8 * g);

  float4v ha[4][4];
#pragma unroll
  for (int n = 0; n < 4; ++n)
#pragma unroll
    for (int t = 0; t < 4; ++t) ha[n][t] = (float4v)(0.0f);

  const size_t koff0 = ((size_t)(wid * 2048) + (size_t)(lane >> 3)) * 1024
                     + (size_t)(h * 64) + (size_t)(((lane & 7) ^ (lane >> 3)) * 8);
  const size_t voff0 = ((size_t)(h * 64) + (size_t)(lane >> 2)) * 8192
                     + (size_t)((wid - 4) * 2048)
                     + (size_t)((((lane & 3) ^ ((lane >> 3) & 3)) * 8));

  auto stage = [&](int step, int b) {
    if (wid < 4) {
      char* kdst = smem + b * 32768 + wid * 4096;
      const unsigned short* ksrc = kb + koff0 + (size_t)step * 32 * 1024;
#pragma unroll
      for (int ii = 0; ii < 4; ++ii)
        gload16(ksrc + ii * 8192, kdst + ii * 1024);
    } else {
      char* vdst = smem + b * 32768 + 16384 + (wid - 4) * 4096;
      const unsigned short* vsrc = vtb + voff0 + (size_t)step * 32;
#pragma unroll
      for (int ii = 0; ii < 4; ++ii)
        gload16(vsrc + (size_t)ii * 16 * 8192, vdst + ii * 1024);
    }
  };

  stage(0, 0);
  stage(1, 1);
  stage(2, 2);
  asm volatile("s_waitcnt vmcnt(8)" ::: "memory");
  __builtin_amdgcn_s_barrier();

  const unsigned voffr = ((unsigned)(g ^ ((rl >> 1) & 3))) << 4;

  for (int to = 0; to < 16; ++to) {
#pragma unroll
    for (int ti = 0; ti < 4; ++ti) {
      const int t = to * 4 + ti;
      char* kbase = smem + ti * 32768;
      char* vbase = kbase + 16384;

      float4v sc[4][2];
      __builtin_amdgcn_s_setprio(1);    // T5: favor this wave through the QK cluster
#pragma unroll
      for (int n = 0; n < 4; ++n) {
        char* kn = kbase + n * 4096;
#pragma unroll
        for (int ss = 0; ss < 2; ++ss) {
          const int srw = ss * 16 + rl;
          const unsigned sw = ((unsigned)(srw & 7)) << 4;
          short8 kf0 = *(const short8*)(kn + srw * 128 + ((16u * (unsigned)g) ^ sw));
          short8 kf1 = *(const short8*)(kn + srw * 128 + ((64u + 16u * (unsigned)g) ^ sw));
          float4v c = (float4v)(0.0f);
          c = __builtin_amdgcn_mfma_f32_16x16x32_bf16(kf0, qf[n][0], c, 0, 0, 0);
          c = __builtin_amdgcn_mfma_f32_16x16x32_bf16(kf1, qf[n][1], c, 0, 0, 0);
          sc[n][ss] = c;
        }
      }
      __builtin_amdgcn_s_setprio(0);

      float ex[4][2][4];
#pragma unroll
      for (int ss = 0; ss < 2; ++ss) {
#pragma unroll
        for (int n = 0; n < 4; ++n)
#pragma unroll
          for (int r = 0; r < 4; ++r)
            ex[n][ss][r] = EXP2(sc[n][ss][r]);
#pragma unroll
        for (int r = 0; r < 4; ++r) {
          float inv = __builtin_amdgcn_rcpf((ex[0][ss][r] + ex[1][ss][r])
                                          + (ex[2][ss][r] + ex[3][ss][r]) + 1e-30f);
          ex[0][ss][r] *= inv; ex[1][ss][r] *= inv;
          ex[2][ss][r] *= inv; ex[3][ss][r] *= inv;
        }
      }
      short8 pf8[4];
#pragma unroll
      for (int n = 0; n < 4; ++n) {
        float4v e0 = {ex[n][0][0], ex[n][0][1], ex[n][0][2], ex[n][0][3]};
        float4v e1 = {ex[n][1][0], ex[n][1][1], ex[n][1][2], ex[n][1][3]};
        pf8[n] = pack8(e0, e1);
      }

      __builtin_amdgcn_s_setprio(1);    // T5: PV cluster
#pragma unroll
      for (int n = 0; n < 4; ++n) {
        char* vn = vbase + n * 4096;
#pragma unroll
        for (int t4 = 0; t4 < 4; ++t4) {
          short8 va = *(const short8*)(vn + (t4 * 16 + rl) * 64 + voffr);
          ha[n][t4] = __builtin_amdgcn_mfma_f32_16x16x32_bf16(va, pf8[n], ha[n][t4], 0, 0, 0);
        }
      }
      __builtin_amdgcn_s_setprio(0);

      if (t + 3 < 64) stage(t + 3, (ti + 3) & 3);
      asm volatile("s_waitcnt vmcnt(8)" ::: "memory");
      __builtin_amdgcn_s_barrier();
    }
  }

#pragma unroll
  for (int n = 0; n < 4; ++n)
#pragma unroll
    for (int tt = 0; tt < 4; ++tt) {
      short4v w = pack4(ha[n][tt][0], ha[n][tt][1], ha[n][tt][2], ha[n][tt][3]);
      size_t off = (size_t)(n * 2048 + l0 + rl) * 1024 + h * 64 + tt * 16 + 4 * g;
      *(short4v*)(hb + off) = w;
    }
}

extern "C" void kernel_launch(void* const* d_in, const int* in_sizes, int n_in,
                              void* d_out, int out_size, void* d_ws, size_t ws_size,
                              hipStream_t stream)
{
  const float* Q  = (const float*)d_in[0];
  const float* K  = (const float*)d_in[1];
  const float* V  = (const float*)d_in[2];
  const float* Wq = (const float*)d_in[3];
  const float* Wo = (const float*)d_in[4];

  unsigned short* qb  = (unsigned short*)d_ws;            // 16 MB each
  unsigned short* kw  = qb + (size_t)8192 * 1024;
  unsigned short* vt  = kw + (size_t)8192 * 1024;         // v^T (s-permuted)
  unsigned short* wqb = vt + (size_t)8192 * 1024;         // Wq bf16, 2 MB
  unsigned short* wob = wqb + (size_t)1024 * 1024;        // Wo bf16, 2 MB
  unsigned short* hw  = qb;  // heads alias q (block-exclusive read-then-write)

  const float CS = 0.18033688011112042f;  // log2(e)/8: folds 1/sqrt(dk) + ln2 into q

  cvt_bf16_2<<<1024, 256, 0, stream>>>(Wq, Wo, wqb, wob);
  gemm_proj3<<<dim3(64, 24), dim3(256), 0, stream>>>(Q, K, V, wqb, qb, kw, vt, CS);
  attn_bn<<<dim3(16, 16), dim3(512), 0, stream>>>(qb, kw, vt, hw);
  gemm_out<<<dim3(64, 8), dim3(256), 0, stream>>>(hw, wob, (float*)d_out, 8192, 1024, 1024);
}